// Round 4
// baseline (201.209 us; speedup 1.0000x reference)
//
#include <hip/hip_runtime.h>
#include <stdint.h>
#include <stddef.h>

typedef __attribute__((ext_vector_type(8))) short bf16x8;
typedef __attribute__((ext_vector_type(4))) float f32x4;
typedef __attribute__((ext_vector_type(4))) int i32x4;

#define NH 128
#define NW 128
#define NC 64
#define NF 256

__device__ __forceinline__ unsigned short f2b(float f) {
  union { float f; uint32_t u; } t; t.f = f;
  uint32_t u = t.u;
  return (unsigned short)((u + 0x7fffu + ((u >> 16) & 1u)) >> 16);
}

// prep: kernel weights in exact per-wave fragment order (same as R4, passed):
//   u16 elem ((fi*9+s)*16 + cf*2 + kk)*512 + lane*8 + e
//     = kern[(s*64 + (kk*4+(lane>>4))*8 + e)*NF + fi*128 + cf*16 + (lane&15)]
__global__ void prep_bt(const float* __restrict__ kr, unsigned short* __restrict__ bt) {
  int t = blockIdx.x * 256 + threadIdx.x;   // [0, 18432)
  int lane = t & 63;
  int kk   = (t >> 6) & 1;
  int cf   = (t >> 7) & 7;
  int rest = t >> 10;          // fi*9 + s
  int s  = rest % 9;
  int fi = rest / 9;
  int l15 = lane & 15, l4 = lane >> 4;
  int col = fi * 128 + cf * 16 + l15;
  int k0  = s * 64 + (kk * 4 + l4) * 8;
  unsigned short* dst = bt + (size_t)t * 8;
  const float* src = kr + (size_t)k0 * NF + col;
  #pragma unroll
  for (int e = 0; e < 8; ++e) dst[e] = f2b(src[(size_t)e * NF]);
}

#define SLOT 16384   // one x-row as bf16: [w=128][cb=8 x 16B], XOR-swizzled

// Strip kernel: block = 8 output rows (one b, one fi half), rolling 4-slot LDS.
// Per row-step: stage ONE new x-row (split in 2 halves, loads issued early),
// 9 shifts of MFMA with register triple-buffered B (period 9 % 3 == 0 -> all
// breg indices static), stores drain async, ONE barrier per row.
__global__ __launch_bounds__(256, 2)
void conv_main(const float* __restrict__ x, const unsigned short* __restrict__ bt,
               const float* __restrict__ bias, float* __restrict__ out)
{
  __shared__ __align__(16) char lds[4 * SLOT];   // 64 KB

  const int tid  = threadIdx.x;
  const int lane = tid & 63;
  const int l15  = lane & 15;
  const int l4   = lane >> 4;
  const int wid  = tid >> 6;
  const int wm   = wid >> 1;    // wave row (2)
  const int wn   = wid & 1;     // wave col (2)

  // XCD-aware bijective swizzle, 512 blocks: 64 per XCD, strips contiguous.
  int bid  = (int)blockIdx.x;
  int work = (bid & 7) * 64 + (bid >> 3);
  int fi    = work & 1;
  int strip = (work >> 1) & 15;
  int bb    = work >> 5;
  int h0 = strip * 8;
  int F0 = fi * 128;

  const char* bimg = (const char*)bt + (size_t)fi * 9 * 16384;
  const int boff = wn * 8192 + lane * 16;   // wave's 4 cf-frags base

  // A-fragment address LUT: alut[dwi][m] for dw = 1-dwi, kk=0 (kk=1 = ^64)
  int alut[3][4];
  #pragma unroll
  for (int dwi = 0; dwi < 3; ++dwi) {
    #pragma unroll
    for (int m = 0; m < 4; ++m) {
      int ws = (wm * 64 + m * 16 + l15 + (1 - dwi)) & 127;
      alut[dwi][m] = ws * 128 + ((l4 ^ (ws & 7)) << 4);
    }
  }

  bf16x8 breg[3][4][2];   // triple buffer, all indices static after unroll

  // ---- prologue: issue B(0) loads, then stage x-rows h0-1..h0+1 -> slots 0..2
  #pragma unroll
  for (int n = 0; n < 4; ++n)
    #pragma unroll
    for (int kk = 0; kk < 2; ++kk)
      breg[0][n][kk] = *(const bf16x8*)(bimg + boff + n * 2048 + kk * 1024);

  #pragma unroll
  for (int i = 0; i < 12; ++i) {
    int idx = tid + i * 256;            // 3072 ds-blocks (3 rows)
    int cb = idx & 7;
    int w  = (idx >> 3) & 127;
    int r  = idx >> 10;                 // 0..2
    int xr = (h0 + r + 127) & 127;      // global x row h0+r-1
    const float* src = x + (((size_t)(bb * NH + xr) * NW + w) * NC + cb * 8);
    float4 a0 = *(const float4*)(src);
    float4 a1 = *(const float4*)(src + 4);
    union { unsigned short u[8]; i32x4 v; } p;
    p.u[0] = f2b(a0.x); p.u[1] = f2b(a0.y); p.u[2] = f2b(a0.z); p.u[3] = f2b(a0.w);
    p.u[4] = f2b(a1.x); p.u[5] = f2b(a1.y); p.u[6] = f2b(a1.z); p.u[7] = f2b(a1.w);
    *(i32x4*)(lds + (r * SLOT + w * 128 + ((cb ^ (w & 7)) << 4))) = p.v;
  }
  __syncthreads();

  float bv[4];
  #pragma unroll
  for (int n = 0; n < 4; ++n) bv[n] = bias[F0 + wn * 64 + n * 16 + l15];

  f32x4 acc[4][4];

  #pragma unroll 1
  for (int j = 0; j < 8; ++j) {
    #pragma unroll
    for (int m = 0; m < 4; ++m)
      #pragma unroll
      for (int n = 0; n < 4; ++n)
        acc[m][n] = (f32x4){0.f, 0.f, 0.f, 0.f};

    const bool dostage = (j < 7);
    const int xr2 = (h0 + j + 2) & 127;           // new x row -> slot (j+3)&3
    const float* xrow = x + (size_t)(bb * NH + xr2) * NW * NC;
    const int wslotb = ((j + 3) & 3) * SLOT;

    // stage half 0: issue loads now (ds-blocks tid, tid+256)
    float4 xv[4];
    int scb0 = tid & 7,        sw0 = (tid >> 3) & 127;
    int scb1 = (tid + 256) & 7, sw1 = ((tid + 256) >> 3) & 127;
    if (dostage) {
      const float* s0 = xrow + sw0 * NC + scb0 * 8;
      const float* s1 = xrow + sw1 * NC + scb1 * 8;
      xv[0] = *(const float4*)(s0); xv[1] = *(const float4*)(s0 + 4);
      xv[2] = *(const float4*)(s1); xv[3] = *(const float4*)(s1 + 4);
    }

    #pragma unroll
    for (int s = 0; s < 9; ++s) {
      // prefetch B((s+1)%9) into buf (s+1)%3 (L2-resident, flies under MFMA)
      {
        const char* bs = bimg + (size_t)(((s + 1) % 9) * 16384) + boff;
        #pragma unroll
        for (int n = 0; n < 4; ++n)
          #pragma unroll
          for (int kk = 0; kk < 2; ++kk)
            breg[(s + 1) % 3][n][kk] = *(const bf16x8*)(bs + n * 2048 + kk * 1024);
      }
      if (s == 5 && dostage) {
        // write half 0, then issue half 1 loads (ds-blocks tid+512, tid+768)
        #pragma unroll
        for (int hblk = 0; hblk < 2; ++hblk) {
          int cb = hblk ? scb1 : scb0;
          int w  = hblk ? sw1  : sw0;
          union { unsigned short u[8]; i32x4 v; } p;
          float4 a0 = xv[hblk * 2], a1 = xv[hblk * 2 + 1];
          p.u[0] = f2b(a0.x); p.u[1] = f2b(a0.y); p.u[2] = f2b(a0.z); p.u[3] = f2b(a0.w);
          p.u[4] = f2b(a1.x); p.u[5] = f2b(a1.y); p.u[6] = f2b(a1.z); p.u[7] = f2b(a1.w);
          *(i32x4*)(lds + (wslotb + w * 128 + ((cb ^ (w & 7)) << 4))) = p.v;
        }
        const float* s2 = xrow + (((tid + 512) >> 3) & 127) * NC + ((tid + 512) & 7) * 8;
        const float* s3 = xrow + (((tid + 768) >> 3) & 127) * NC + ((tid + 768) & 7) * 8;
        xv[0] = *(const float4*)(s2); xv[1] = *(const float4*)(s2 + 4);
        xv[2] = *(const float4*)(s3); xv[3] = *(const float4*)(s3 + 4);
      }
      const int dwi = s / 3;                              // static
      const int slotb = ((j + 2 - (s % 3)) & 3) * SLOT;   // x-row slot for this shift
      #pragma unroll
      for (int kk = 0; kk < 2; ++kk) {
        bf16x8 af[4];
        #pragma unroll
        for (int m = 0; m < 4; ++m) {
          int a = slotb + alut[dwi][m];
          if (kk) a ^= 64;
          af[m] = *(const bf16x8*)(lds + a);
        }
        #pragma unroll
        for (int m = 0; m < 4; ++m)
          #pragma unroll
          for (int n = 0; n < 4; ++n)
            acc[m][n] = __builtin_amdgcn_mfma_f32_16x16x32_bf16(
                af[m], breg[s % 3][n][kk], acc[m][n], 0, 0, 0);
      }
    }

    // epilogue: bias + stores for row j (drain async over next step)
    {
      int hh = h0 + j;
      size_t rowbase = (size_t)(bb * NH + hh) * NW;
      #pragma unroll
      for (int m = 0; m < 4; ++m) {
        #pragma unroll
        for (int jj = 0; jj < 4; ++jj) {
          int wr = wm * 64 + m * 16 + l4 * 4 + jj;
          float* orow = out + (rowbase + wr) * NF + F0 + wn * 64;
          #pragma unroll
          for (int n = 0; n < 4; ++n)
            orow[n * 16 + l15] = acc[m][n][jj] + bv[n];
        }
      }
    }

    // finish staging: write half 1
    if (dostage) {
      #pragma unroll
      for (int hblk = 0; hblk < 2; ++hblk) {
        int idx = tid + 512 + hblk * 256;
        int cb = idx & 7;
        int w  = (idx >> 3) & 127;
        union { unsigned short u[8]; i32x4 v; } p;
        float4 a0 = xv[hblk * 2], a1 = xv[hblk * 2 + 1];
        p.u[0] = f2b(a0.x); p.u[1] = f2b(a0.y); p.u[2] = f2b(a0.z); p.u[3] = f2b(a0.w);
        p.u[4] = f2b(a1.x); p.u[5] = f2b(a1.y); p.u[6] = f2b(a1.z); p.u[7] = f2b(a1.w);
        *(i32x4*)(lds + (wslotb + w * 128 + ((cb ^ (w & 7)) << 4))) = p.v;
      }
    }
    __syncthreads();
  }
}

extern "C" void kernel_launch(void* const* d_in, const int* in_sizes, int n_in,
                              void* d_out, int out_size, void* d_ws, size_t ws_size,
                              hipStream_t stream) {
  const float* x    = (const float*)d_in[0];
  const float* kern = (const float*)d_in[1];
  const float* bias = (const float*)d_in[2];
  float* out = (float*)d_out;
  unsigned short* bt = (unsigned short*)d_ws;   // 294912 bytes needed

  prep_bt<<<dim3(72), dim3(256), 0, stream>>>(kern, bt);
  conv_main<<<dim3(512), dim3(256), 0, stream>>>(x, bt, bias, out);
}

// Round 5
// 131.271 us; speedup vs baseline: 1.5328x; 1.5328x over previous
//
#include <hip/hip_runtime.h>
#include <stdint.h>
#include <stddef.h>

typedef __attribute__((ext_vector_type(8))) short bf16x8;
typedef __attribute__((ext_vector_type(4))) float f32x4;
typedef __attribute__((ext_vector_type(4))) int i32x4;

#define NH 128
#define NW 128
#define NC 64
#define NF 256

__device__ __forceinline__ unsigned short f2b(float f) {
  union { float f; uint32_t u; } t; t.f = f;
  uint32_t u = t.u;
  return (unsigned short)((u + 0x7fffu + ((u >> 16) & 1u)) >> 16);
}

// prep: kernel weights in exact per-wave fragment order (proven R3/R4):
//   u16 elem ((fi*9+s)*16 + cf*2 + kk)*512 + lane*8 + e
//     = kern[(s*64 + (kk*4+(lane>>4))*8 + e)*NF + fi*128 + cf*16 + (lane&15)]
__global__ void prep_bt(const float* __restrict__ kr, unsigned short* __restrict__ bt) {
  int t = blockIdx.x * 256 + threadIdx.x;   // [0, 18432)
  int lane = t & 63;
  int kk   = (t >> 6) & 1;
  int cf   = (t >> 7) & 7;
  int rest = t >> 10;          // fi*9 + s
  int s  = rest % 9;
  int fi = rest / 9;
  int l15 = lane & 15, l4 = lane >> 4;
  int col = fi * 128 + cf * 16 + l15;
  int k0  = s * 64 + (kk * 4 + l4) * 8;
  unsigned short* dst = bt + (size_t)t * 8;
  const float* src = kr + (size_t)k0 * NF + col;
  #pragma unroll
  for (int e = 0; e < 8; ++e) dst[e] = f2b(src[(size_t)e * NF]);
}

// LDS: A only (48 KB), 3 rows x [w=128][cb=8 x 16B] XOR-swizzled.
// B: per-wave register double-buffer from L2-resident prep table.
// Main loop barrier-free (R3 structure, passed). NEW: epilogue transposes
// acc through the dead x-LDS so every global store instruction writes
// 1024 contiguous bytes (8 FULL 128B lines) -> no RFO / partial evictions.
__global__ __launch_bounds__(256, 3)
void conv_main(const float* __restrict__ x, const unsigned short* __restrict__ bt,
               const float* __restrict__ bias, float* __restrict__ out)
{
  __shared__ __align__(16) char lds[3 * 16384];   // 48 KB; reused by epilogue

  const int tid  = threadIdx.x;
  const int lane = tid & 63;
  const int l15  = lane & 15;
  const int l4   = lane >> 4;
  const int wid  = tid >> 6;
  const int wm   = wid >> 1;    // wave row (2)
  const int wn   = wid & 1;     // wave col (2)

  // XCD-aware bijective swizzle: nwg=4096, 8 XCDs, 512 per XCD.
  // Consecutive works on one XCD share fi pairs + adjacent h -> x L2 reuse.
  int bid  = (int)blockIdx.x;
  int work = (bid & 7) * 512 + (bid >> 3);
  int mi = work >> 1;           // 0..2047 : (b,h) flat
  int fi = work & 1;            // F half
  int bb = mi >> 7;
  int hh = mi & 127;
  int F0 = fi * 128;

  const char* bimg = (const char*)bt + (size_t)fi * 9 * 16384;
  const int boff = (wn * 4) * 2048 + lane * 16;

  bf16x8 breg[2][4][2];   // [buf][n][kk] — fully unrolled => static idx

  // ---- issue B(0) register loads first (fly under A-staging VALU) ----
  #pragma unroll
  for (int n = 0; n < 4; ++n)
    #pragma unroll
    for (int kk = 0; kk < 2; ++kk)
      breg[0][n][kk] = *(const bf16x8*)(bimg + boff + n * 2048 + kk * 1024);

  // ---- stage A: x rows h-1,h,h+1 (circular) -> bf16 swizzled LDS, once ----
  #pragma unroll
  for (int i = 0; i < 12; ++i) {
    int idx = tid + i * 256;            // 3072 16B-blocks
    int cb = idx & 7;
    int w  = (idx >> 3) & 127;
    int r  = idx >> 10;                 // 0..2
    int xr = (hh + r + 127) & 127;
    const float* src = x + (((size_t)(bb * NH + xr) * NW + w) * NC + cb * 8);
    float4 a0 = *(const float4*)(src);
    float4 a1 = *(const float4*)(src + 4);
    union { unsigned short u[8]; i32x4 v; } p;
    p.u[0] = f2b(a0.x); p.u[1] = f2b(a0.y); p.u[2] = f2b(a0.z); p.u[3] = f2b(a0.w);
    p.u[4] = f2b(a1.x); p.u[5] = f2b(a1.y); p.u[6] = f2b(a1.z); p.u[7] = f2b(a1.w);
    *(i32x4*)(lds + (r * 16384 + w * 128 + ((cb ^ (w & 7)) << 4))) = p.v;
  }
  __syncthreads();    // A tile ready, read-only during main loop

  f32x4 acc[4][4];
  #pragma unroll
  for (int m = 0; m < 4; ++m)
    #pragma unroll
    for (int n = 0; n < 4; ++n)
      acc[m][n] = (f32x4){0.f, 0.f, 0.f, 0.f};

  #pragma unroll
  for (int s = 0; s < 9; ++s) {
    const int cur = s & 1;
    if (s < 8) {  // prefetch next shift's B into the other register set (L2)
      const char* src = bimg + (size_t)(s + 1) * 16384 + boff;
      #pragma unroll
      for (int n = 0; n < 4; ++n)
        #pragma unroll
        for (int kk = 0; kk < 2; ++kk)
          breg[cur ^ 1][n][kk] = *(const bf16x8*)(src + n * 2048 + kk * 1024);
    }
    const int r  = 2 - (s % 3);     // staged x-row index
    const int dw = 1 - (s / 3);     // circular w offset
    const char* abase = lds + r * 16384;
    #pragma unroll
    for (int kk = 0; kk < 2; ++kk) {
      bf16x8 af[4];
      const int kb = kk * 4 + l4;
      #pragma unroll
      for (int m = 0; m < 4; ++m) {
        int wsrc = (wm * 64 + m * 16 + l15 + dw) & 127;
        af[m] = *(const bf16x8*)(abase + wsrc * 128 + ((kb ^ (wsrc & 7)) << 4));
      }
      #pragma unroll
      for (int m = 0; m < 4; ++m)
        #pragma unroll
        for (int n = 0; n < 4; ++n)
          acc[m][n] = __builtin_amdgcn_mfma_f32_16x16x32_bf16(af[m], breg[cur][n][kk], acc[m][n], 0, 0, 0);
    }
  }

  // ---- epilogue: bias + FULL-LINE stores via LDS transpose ----
  float bv[4];
  #pragma unroll
  for (int n = 0; n < 4; ++n) bv[n] = bias[F0 + wn * 64 + n * 16 + l15];

  __syncthreads();                      // x-LDS reads complete -> reuse as eb
  float* eb = (float*)lds;              // [64 rows][132 floats] padded tile

  #pragma unroll
  for (int chunk = 0; chunk < 2; ++chunk) {
    if (wm == chunk) {                  // owning wave-pair deposits acc+bias
      #pragma unroll
      for (int m = 0; m < 4; ++m)
        #pragma unroll
        for (int jj = 0; jj < 4; ++jj) {
          int r = m * 16 + l4 * 4 + jj;               // 0..63 chunk-local
          #pragma unroll
          for (int n = 0; n < 4; ++n)
            eb[r * 132 + wn * 64 + n * 16 + l15] = acc[m][n][jj] + bv[n];
        }
    }
    __syncthreads();
    // all 4 waves store: per instr 64 lanes x float4 = 1024B contiguous
    size_t obase = ((size_t)mi * 128 + chunk * 64) * NF + F0;
    #pragma unroll
    for (int i = 0; i < 8; ++i) {
      int r = i * 8 + wid * 2 + (lane >> 5);          // 0..63
      int c = (lane & 31) * 4;
      f32x4 v = *(const f32x4*)(eb + r * 132 + c);
      *(f32x4*)(out + obase + (size_t)r * NF + c) = v;
    }
    if (chunk == 0) __syncthreads();    // before chunk 1 overwrites eb
  }
}

extern "C" void kernel_launch(void* const* d_in, const int* in_sizes, int n_in,
                              void* d_out, int out_size, void* d_ws, size_t ws_size,
                              hipStream_t stream) {
  const float* x    = (const float*)d_in[0];
  const float* kern = (const float*)d_in[1];
  const float* bias = (const float*)d_in[2];
  float* out = (float*)d_out;
  unsigned short* bt = (unsigned short*)d_ws;   // 294912 bytes needed

  prep_bt<<<dim3(72), dim3(256), 0, stream>>>(kern, bt);
  conv_main<<<dim3(4096), dim3(256), 0, stream>>>(x, bt, bias, out);
}